// Round 5
// baseline (371.590 us; speedup 1.0000x reference)
//
#include <hip/hip_runtime.h>
#include <hip/hip_bf16.h>

#define NN 2048
#define BB 8
#define TROW 128928   // sum_{d=1..64} (2047-d)

// ---------------- k_left: R[b][i][k] = dot(x[b,i,:], wl[k,:]), k=(c*3+dh) in [0,15) ----------
// grid 1024 = 8 b x 128 rowgroups(16 rows); block 256 = 4 waves; wave handles 4 rows.
// Also zeroes psum[64] (block 0) so no separate memset dispatch is needed.
__global__ __launch_bounds__(256) void k_left(const float* __restrict__ x,
                                              const float* __restrict__ wl,
                                              float* __restrict__ R,
                                              float* __restrict__ psum) {
    if (blockIdx.x == 0 && threadIdx.x < 64) psum[threadIdx.x] = 0.f;
    __shared__ float red[4][60 * 65];
    int b = blockIdx.x >> 7;
    int rbase = (blockIdx.x & 127) << 4;
    int wv = threadIdx.x >> 6, lane = threadIdx.x & 63;
    int r0 = rbase + wv * 4;
    const float* xp = x + ((size_t)(b * NN + r0)) * NN;

    float acc[4][15];
#pragma unroll
    for (int r = 0; r < 4; r++)
#pragma unroll
        for (int k = 0; k < 15; k++) acc[r][k] = 0.f;

    for (int seg = 0; seg < 8; seg++) {
        int j0 = seg * 256 + lane * 4;
        float4 xv[4];
#pragma unroll
        for (int r = 0; r < 4; r++) xv[r] = *(const float4*)(xp + (size_t)r * NN + j0);
#pragma unroll
        for (int k = 0; k < 15; k++) {
            float4 w4 = *(const float4*)(wl + (size_t)k * NN + j0);
#pragma unroll
            for (int r = 0; r < 4; r++) {
                acc[r][k] = fmaf(xv[r].x, w4.x, acc[r][k]);
                acc[r][k] = fmaf(xv[r].y, w4.y, acc[r][k]);
                acc[r][k] = fmaf(xv[r].z, w4.z, acc[r][k]);
                acc[r][k] = fmaf(xv[r].w, w4.w, acc[r][k]);
            }
        }
    }
#pragma unroll
    for (int r = 0; r < 4; r++)
#pragma unroll
        for (int k = 0; k < 15; k++) red[wv][(r * 15 + k) * 65 + lane] = acc[r][k];
    __syncthreads();
    if (lane < 60) {
        const float* rp = &red[wv][lane * 65];
        float s = 0.f;
#pragma unroll
        for (int j = 0; j < 64; j++) s += rp[j];
        int r = lane / 15, k = lane - r * 15;
        R[(size_t)(b * NN + r0 + r) * 16 + k] = s;
    }
}

// ---------------- k_right: CSp[rc][b][k][j] = sum_{h in rc-chunk} x[b,h,j]*wr[c,h,dw] --------
// grid 512 = 8 b x 8 colchunks(256) x 8 rowchunks(256); block 512 = 8 waves; 2 blocks/CU.
// Wave handles rows wv+8i, i in [0,32); K-loop batched 8x4 with 4 loads in flight.
__global__ __launch_bounds__(512) void k_right(const float* __restrict__ x,
                                               const float* __restrict__ wr,
                                               float* __restrict__ CSp) {
    __shared__ float wf[256 * 16];   // 16 KB: transposed weights for this row chunk
    __shared__ float CS_l[15 * 256]; // 15 KB: block-level column sums
    int b = blockIdx.x >> 6;
    int rem = blockIdx.x & 63;
    int jc = rem >> 3, rc = rem & 7;
    int j0 = jc * 256, r0 = rc * 256;
    int tid = threadIdx.x;
    int wv = tid >> 6, lane = tid & 63;

    // stage weights with inline transpose (scalar, L2-hot: wr is 120 KB)
    for (int idx = tid; idx < 256 * 15; idx += 512) {
        int hh = idx / 15, k = idx - hh * 15;
        int c = k / 3, dw = k - c * 3;
        wf[hh * 16 + k] = wr[c * (NN * 3) + (r0 + hh) * 3 + dw];
    }
    // zero block sums
    for (int idx = tid; idx < 15 * 256; idx += 512) CS_l[idx] = 0.f;
    __syncthreads();

    float acc[15][4];
#pragma unroll
    for (int k = 0; k < 15; k++)
#pragma unroll
        for (int e = 0; e < 4; e++) acc[k][e] = 0.f;

    const float* xp = x + ((size_t)b * NN + r0) * NN + j0 + lane * 4;
    for (int ib = 0; ib < 8; ib++) {
        int rbase = wv + 32 * ib;
        float4 xv[4];
#pragma unroll
        for (int q = 0; q < 4; q++)
            xv[q] = *(const float4*)(xp + (size_t)(rbase + 8 * q) * NN);
#pragma unroll
        for (int q = 0; q < 4; q++) {
            const float* wrow = &wf[(rbase + 8 * q) * 16];
            float4 w0 = *(const float4*)(wrow);
            float4 w1 = *(const float4*)(wrow + 4);
            float4 w2 = *(const float4*)(wrow + 8);
            float4 w3 = *(const float4*)(wrow + 12);
            float wk[15] = {w0.x, w0.y, w0.z, w0.w, w1.x, w1.y, w1.z, w1.w,
                            w2.x, w2.y, w2.z, w2.w, w3.x, w3.y, w3.z};
#pragma unroll
            for (int k = 0; k < 15; k++) {
                acc[k][0] = fmaf(xv[q].x, wk[k], acc[k][0]);
                acc[k][1] = fmaf(xv[q].y, wk[k], acc[k][1]);
                acc[k][2] = fmaf(xv[q].z, wk[k], acc[k][2]);
                acc[k][3] = fmaf(xv[q].w, wk[k], acc[k][3]);
            }
        }
    }
    // cross-wave reduce in LDS (8 contenders per address)
    int l4 = lane * 4;
#pragma unroll
    for (int k = 0; k < 15; k++)
#pragma unroll
        for (int e = 0; e < 4; e++) atomicAdd(&CS_l[k * 256 + l4 + e], acc[k][e]);
    __syncthreads();
    // write partial (plain stores, coalesced)
    float* outp = CSp + (((size_t)rc * BB + b) * 16) * NN + j0;
    for (int idx = tid; idx < 15 * 256; idx += 512) {
        int k = idx >> 8, col = idx & 255;
        outp[(size_t)k * NN + col] = CS_l[idx];
    }
}

// ---------------- k_chainC: combine(R,CSp)+bias -> 6 conv layers -> sigmoid head -------------
// grid 128 = 8 b x 16 chunks(128 cols); halo 6 each side -> ext 140 positions.
__global__ __launch_bounds__(256) void k_chainC(const float* __restrict__ R,
                                                const float* __restrict__ CSp,
                                                const float* __restrict__ bl,
                                                const float* __restrict__ br,
                                                const float* __restrict__ wA, const float* __restrict__ bA,
                                                const float* __restrict__ wB, const float* __restrict__ bB,
                                                const float* __restrict__ wT, const float* __restrict__ bT,
                                                const float* __restrict__ wm, const float* __restrict__ bm,
                                                float* __restrict__ LEFT, float* __restrict__ RIGHT) {
    __shared__ float buf0[10][144], buf1[10][144];
    __shared__ float W[3][10][10][3];
    __shared__ float Bs[3][10];
    __shared__ float Wm[2][10], Bm[2];
    int b = blockIdx.x >> 4;
    int c0 = (blockIdx.x & 15) << 7;
    int tid = threadIdx.x;

    for (int idx = tid; idx < 900; idx += 256) {
        int set = idx / 300, rem = idx - set * 300;
        int o = rem / 30, rem2 = rem - o * 30, c = rem2 / 3, kk = rem2 - c * 3;
        float u;
        if (set == 0) u = wA[o * 30 + c * 3 + kk];
        else if (set == 1) u = wB[o * 30 + c * 3 + kk];
        else u = wT[c * 30 + o * 3 + (2 - kk)];   // wTc[o,c,k] = wT[c,o,2-k]
        W[set][o][c][kk] = u;
    }
    if (tid < 30) {
        float v = (tid < 10) ? bA[tid] : (tid < 20) ? bB[tid - 10] : bT[tid - 20];
        Bs[tid / 10][tid % 10] = v;
    }
    if (tid < 20) Wm[tid / 10][tid % 10] = wm[tid];
    if (tid < 2) Bm[tid] = bm[tid];

    // fused combine: build the 10x140 input window directly from R / CSp
    for (int idx = tid; idx < 1400; idx += 256) {
        int ch = idx / 140, p = idx - ch * 140;
        int g = c0 - 6 + p;
        float v = 0.f;
        if (g >= 0 && g < NN) {
            if (ch < 5) {
                v = bl[ch];
#pragma unroll
                for (int dh = 0; dh < 3; dh++) {
                    int r = g + dh - 1;
                    if (r >= 0 && r < NN) v += R[(size_t)(b * NN + r) * 16 + ch * 3 + dh];
                }
            } else {
                int c = ch - 5;
                v = br[c];
#pragma unroll
                for (int dw = 0; dw < 3; dw++) {
                    int j = g + dw - 1;
                    if (j >= 0 && j < NN) {
#pragma unroll
                        for (int rc = 0; rc < 8; rc++)
                            v += CSp[(((size_t)rc * BB + b) * 16 + c * 3 + dw) * NN + j];
                    }
                }
            }
        }
        buf0[ch][p] = v;
    }
    __syncthreads();

    float(*in)[144] = buf0;
    float(*out)[144] = buf1;
    for (int layer = 0; layer < 6; layer++) {
        int set = (layer == 0) ? 0 : (layer < 3 ? 1 : 2);
        int lo = layer + 1;  // valid p range [lo, 140-lo)
        for (int idx = tid; idx < 1400; idx += 256) {
            int o = idx / 140, p = idx - o * 140;
            if (p >= lo && p < 140 - lo) {
                float s = Bs[set][o];
#pragma unroll
                for (int c = 0; c < 10; c++) {
                    const float* ip = &in[c][p];
                    s = fmaf(ip[-1], W[set][o][c][0], s);
                    s = fmaf(ip[0], W[set][o][c][1], s);
                    s = fmaf(ip[1], W[set][o][c][2], s);
                }
                s = s > 0.f ? s : 0.f;
                int g = c0 - 6 + p;
                if (g < 0 || g >= NN) s = 0.f;  // reproduce zero padding at global edges
                out[o][p] = s;
            }
        }
        __syncthreads();
        float(*tmp)[144] = in; in = out; out = tmp;
    }
    // 1x1 conv to 2ch + sigmoid; write the 128 owned cols
    {
        int idx = tid;  // 256 = 2 ch x 128 cols
        int o = idx >> 7, pp = idx & 127;
        int p = 6 + pp;
        float s = Bm[o];
#pragma unroll
        for (int c = 0; c < 10; c++) s = fmaf(in[c][p], Wm[o][c], s);
        float sig = 1.f / (1.f + __expf(-s));
        (o ? RIGHT : LEFT)[b * NN + c0 + pp] = sig;
    }
}

// ---------------- k_diagmass: stage exp(diag) tile, compute p, write P + psum atomics --------
// grid 256 = 8 b x 32 i-tiles(64); block 256 = 4 waves; wave wv handles dm1 = wv*16..wv*16+15.
__global__ __launch_bounds__(256) void k_diagmass(const float* __restrict__ x,
                                                  const float* __restrict__ LEFT,
                                                  const float* __restrict__ RIGHT,
                                                  float* __restrict__ P,
                                                  float* __restrict__ psum) {
    __shared__ float T[65][65];   // T[r][dm1] = exp(x[b, i0+r, i0+r+dm1+1]), +1 halo row
    __shared__ float psl[64];
    int b = blockIdx.x >> 5;
    int i0 = (blockIdx.x & 31) << 6;
    int tid = threadIdx.x;

    // stage: 65 rows x 64 diag offsets, coalesced along the row
    for (int idx = tid; idx < 65 * 64; idx += 256) {
        int r = idx >> 6, dm1 = idx & 63;
        int row = i0 + r;
        int col = row + dm1 + 1;
        float v = 0.f;
        if (row < NN && col < NN) v = __expf(x[((size_t)b * NN + row) * NN + col]);
        T[r][dm1] = v;
    }
    __syncthreads();

    int wv = tid >> 6, lane = tid & 63;
    int i = i0 + lane;
    const float* lf = LEFT + b * NN;
    const float* rt = RIGHT + b * NN;
#pragma unroll
    for (int s = 0; s < 16; s++) {
        int dm1 = wv * 16 + s;
        int d = dm1 + 1;
        int L = (NN - 1) - d;
        float p = 0.f;
        if (i < L) {
            float mi = T[lane + 1][dm1] * rt[i + 1] + T[lane][dm1] * lf[d + i];
            float mo = rt[i] + lf[d + 1 + i];
            p = __logf(mi / mo);
            P[((size_t)dm1 * BB + b) * NN + i] = p;
        }
        float s64 = p;
        for (int off = 32; off; off >>= 1) s64 += __shfl_down(s64, off);
        if (lane == 0) psl[dm1] = s64;
    }
    __syncthreads();
    if (tid < 64) atomicAdd(&psum[tid], psl[tid]);
}

// ---------------- k_out: out = P - psum[d]/(8L), f32 ------------------------------------------
__global__ __launch_bounds__(1024) void k_out(const float* __restrict__ P,
                                              const float* __restrict__ psum,
                                              float* __restrict__ outp) {
    int dm1 = blockIdx.x >> 2, q = blockIdx.x & 3;
    int d = dm1 + 1;
    int L = (NN - 1) - d;
    int tid = threadIdx.x;
    int b2 = tid >> 9, ii = tid & 511;
    int i = q * 512 + ii;
    if (i >= L) return;
    float mean = psum[dm1] / (float)(8 * L);
    size_t off0 = (size_t)dm1 * (NN - 1) - (size_t)dm1 * (dm1 + 1) / 2;
#pragma unroll
    for (int bs = 0; bs < 4; bs++) {
        int b = b2 + bs * 2;
        outp[(size_t)b * TROW + off0 + i] = P[((size_t)dm1 * BB + b) * NN + i] - mean;
    }
}

extern "C" void kernel_launch(void* const* d_in, const int* in_sizes, int n_in,
                              void* d_out, int out_size, void* d_ws, size_t ws_size,
                              hipStream_t stream) {
    const float* x = (const float*)d_in[0];
    const float* wl = (const float*)d_in[1];
    const float* bl = (const float*)d_in[2];
    const float* wr = (const float*)d_in[3];
    const float* br = (const float*)d_in[4];
    const float* wA = (const float*)d_in[5];
    const float* bA = (const float*)d_in[6];
    const float* wB = (const float*)d_in[7];
    const float* bB = (const float*)d_in[8];
    const float* wT = (const float*)d_in[9];
    const float* bT = (const float*)d_in[10];
    const float* wm = (const float*)d_in[11];
    const float* bm = (const float*)d_in[12];

    float* ws = (float*)d_ws;
    float* R    = ws;              // 8*2048*16        = 262144 f
    float* CSp  = ws + 262144;     // 8*8*16*2048      = 2097152 f
    float* LEFT = ws + 2359296;    // 8*2048           = 16384 f
    float* RIGHT= ws + 2375680;    // 8*2048           = 16384 f
    float* P    = ws + 2392064;    // 64*8*2048        = 1048576 f
    float* psum = ws + 3440640;    // 64 f

    k_left<<<1024, 256, 0, stream>>>(x, wl, R, psum);
    k_right<<<512, 512, 0, stream>>>(x, wr, CSp);
    k_chainC<<<128, 256, 0, stream>>>(R, CSp, bl, br, wA, bA, wB, bB, wT, bT, wm, bm, LEFT, RIGHT);
    k_diagmass<<<256, 256, 0, stream>>>(x, LEFT, RIGHT, P, psum);
    k_out<<<256, 1024, 0, stream>>>(P, psum, (float*)d_out);
}

// Round 6
// 329.650 us; speedup vs baseline: 1.1272x; 1.1272x over previous
//
#include <hip/hip_runtime.h>
#include <hip/hip_bf16.h>

#define NN 2048
#define BB 8
#define TROW 128928   // sum_{d=1..64} (2047-d)

// ---------------- k_left: R[b][i][k] = dot(x[b,i,:], wl[k,:]), k=(c*3+dh) in [0,15) ----------
// grid 2048 = 8 b x 256 rowgroups(8 rows); block 256 = 4 waves; wave handles 2 rows (30 acc).
// Side jobs: blocks 0..127 fill WF (transposed wr); block 0 zeroes psum.
__global__ __launch_bounds__(256) void k_left(const float* __restrict__ x,
                                              const float* __restrict__ wl,
                                              const float* __restrict__ wr,
                                              float* __restrict__ R,
                                              float* __restrict__ WF,
                                              float* __restrict__ psum) {
    if (blockIdx.x == 0 && threadIdx.x < 64) psum[threadIdx.x] = 0.f;
    if (blockIdx.x < 128) {
        int idx = blockIdx.x * 256 + threadIdx.x;  // 32768 = 2048*16
        int h = idx >> 4, k = idx & 15;
        float v = 0.f;
        if (k < 15) {
            int c = k / 3, dw = k - c * 3;
            v = wr[c * (NN * 3) + h * 3 + dw];
        }
        WF[idx] = v;
    }
    __shared__ float red[4][30 * 65];
    int b = blockIdx.x >> 8;
    int rg = blockIdx.x & 255;
    int wv = threadIdx.x >> 6, lane = threadIdx.x & 63;
    int r0 = rg * 8 + wv * 2;
    const float* xp = x + ((size_t)(b * NN + r0)) * NN;

    float acc[2][15];
#pragma unroll
    for (int r = 0; r < 2; r++)
#pragma unroll
        for (int k = 0; k < 15; k++) acc[r][k] = 0.f;

    for (int seg = 0; seg < 8; seg++) {
        int j0 = seg * 256 + lane * 4;
        float4 xv[2];
#pragma unroll
        for (int r = 0; r < 2; r++) xv[r] = *(const float4*)(xp + (size_t)r * NN + j0);
#pragma unroll
        for (int k = 0; k < 15; k++) {
            float4 w4 = *(const float4*)(wl + (size_t)k * NN + j0);
#pragma unroll
            for (int r = 0; r < 2; r++) {
                acc[r][k] = fmaf(xv[r].x, w4.x, acc[r][k]);
                acc[r][k] = fmaf(xv[r].y, w4.y, acc[r][k]);
                acc[r][k] = fmaf(xv[r].z, w4.z, acc[r][k]);
                acc[r][k] = fmaf(xv[r].w, w4.w, acc[r][k]);
            }
        }
    }
#pragma unroll
    for (int r = 0; r < 2; r++)
#pragma unroll
        for (int k = 0; k < 15; k++) red[wv][(r * 15 + k) * 65 + lane] = acc[r][k];
    __syncthreads();
    if (lane < 30) {
        const float* rp = &red[wv][lane * 65];
        float s = 0.f;
#pragma unroll
        for (int j = 0; j < 64; j++) s += rp[j];
        int r = lane / 15, k = lane - r * 15;
        R[(size_t)(b * NN + r0 + r) * 16 + k] = s;
    }
}

// ---------------- k_right: CSp[rc][b][k][j] = sum_{h in rc chunk} x[b,h,j]*WF[h][k] ----------
// grid 256 = 8 b x 2 jc(1024 cols) x 16 rc(128 rows); block 512 = 8 waves.
// Wave owns 128 cols (lane*2 within), iterates ALL 128 rows -> complete partial, no LDS.
// Weights via block-uniform loads from WF (s_load path). 30 acc/thread, 8 loads in flight.
__global__ __launch_bounds__(512) void k_right(const float* __restrict__ x,
                                               const float* __restrict__ WF,
                                               float* __restrict__ CSp) {
    int b = blockIdx.x >> 5;
    int rem = blockIdx.x & 31;
    int jc = rem >> 4, rc = rem & 15;
    int r0 = rc * 128;
    int w = threadIdx.x >> 6, lane = threadIdx.x & 63;
    int c0 = jc * 1024 + w * 128 + lane * 2;
    const float* xp = x + ((size_t)b * NN + r0) * NN + c0;

    float acc[15][2];
#pragma unroll
    for (int k = 0; k < 15; k++) { acc[k][0] = 0.f; acc[k][1] = 0.f; }

    for (int rb = 0; rb < 16; rb++) {
        float2 xv[8];
#pragma unroll
        for (int q = 0; q < 8; q++)
            xv[q] = *(const float2*)(xp + (size_t)(rb * 8 + q) * NN);
#pragma unroll
        for (int q = 0; q < 8; q++) {
            const float* wrow = WF + (size_t)(r0 + rb * 8 + q) * 16;  // block-uniform -> SGPR
#pragma unroll
            for (int k = 0; k < 15; k++) {
                float wk = wrow[k];
                acc[k][0] = fmaf(xv[q].x, wk, acc[k][0]);
                acc[k][1] = fmaf(xv[q].y, wk, acc[k][1]);
            }
        }
    }
    float* outp = CSp + ((size_t)(rc * BB + b) * 16) * NN + c0;
#pragma unroll
    for (int k = 0; k < 15; k++) {
        float2 v; v.x = acc[k][0]; v.y = acc[k][1];
        *(float2*)(outp + (size_t)k * NN) = v;
    }
}

// ---------------- k_csum: CS[b][k][j] = sum_{rc<16} CSp[rc][b][k][j] -------------------------
// grid 256 x block 256; thread handles one float4 (65536 total).
__global__ __launch_bounds__(256) void k_csum(const float* __restrict__ CSp,
                                              float* __restrict__ CS) {
    int vid = blockIdx.x * 256 + threadIdx.x;  // float4 index in [0, 65536)
    const float4* src = (const float4*)CSp;
    float4 s = src[vid];
#pragma unroll
    for (int rc = 1; rc < 16; rc++) {
        float4 v = src[vid + rc * 65536];
        s.x += v.x; s.y += v.y; s.z += v.z; s.w += v.w;
    }
    ((float4*)CS)[vid] = s;
}

// ---------------- k_chainC: combine(R,CS)+bias -> 6 conv layers -> sigmoid head --------------
// grid 128 = 8 b x 16 chunks(128 cols); halo 6 each side -> ext 140 positions.
__global__ __launch_bounds__(256) void k_chainC(const float* __restrict__ R,
                                                const float* __restrict__ CS,
                                                const float* __restrict__ bl,
                                                const float* __restrict__ br,
                                                const float* __restrict__ wA, const float* __restrict__ bA,
                                                const float* __restrict__ wB, const float* __restrict__ bB,
                                                const float* __restrict__ wT, const float* __restrict__ bT,
                                                const float* __restrict__ wm, const float* __restrict__ bm,
                                                float* __restrict__ LEFT, float* __restrict__ RIGHT) {
    __shared__ float buf0[10][144], buf1[10][144];
    __shared__ float W[3][10][10][3];
    __shared__ float Bs[3][10];
    __shared__ float Wm[2][10], Bm[2];
    int b = blockIdx.x >> 4;
    int c0 = (blockIdx.x & 15) << 7;
    int tid = threadIdx.x;

    for (int idx = tid; idx < 900; idx += 256) {
        int set = idx / 300, rem = idx - set * 300;
        int o = rem / 30, rem2 = rem - o * 30, c = rem2 / 3, kk = rem2 - c * 3;
        float u;
        if (set == 0) u = wA[o * 30 + c * 3 + kk];
        else if (set == 1) u = wB[o * 30 + c * 3 + kk];
        else u = wT[c * 30 + o * 3 + (2 - kk)];   // wTc[o,c,k] = wT[c,o,2-k]
        W[set][o][c][kk] = u;
    }
    if (tid < 30) {
        float v = (tid < 10) ? bA[tid] : (tid < 20) ? bB[tid - 10] : bT[tid - 20];
        Bs[tid / 10][tid % 10] = v;
    }
    if (tid < 20) Wm[tid / 10][tid % 10] = wm[tid];
    if (tid < 2) Bm[tid] = bm[tid];

    // fused combine: build the 10x140 input window directly from R / CS
    for (int idx = tid; idx < 1400; idx += 256) {
        int ch = idx / 140, p = idx - ch * 140;
        int g = c0 - 6 + p;
        float v = 0.f;
        if (g >= 0 && g < NN) {
            if (ch < 5) {
                v = bl[ch];
#pragma unroll
                for (int dh = 0; dh < 3; dh++) {
                    int r = g + dh - 1;
                    if (r >= 0 && r < NN) v += R[(size_t)(b * NN + r) * 16 + ch * 3 + dh];
                }
            } else {
                int c = ch - 5;
                v = br[c];
#pragma unroll
                for (int dw = 0; dw < 3; dw++) {
                    int j = g + dw - 1;
                    if (j >= 0 && j < NN)
                        v += CS[((size_t)b * 16 + c * 3 + dw) * NN + j];
                }
            }
        }
        buf0[ch][p] = v;
    }
    __syncthreads();

    float(*in)[144] = buf0;
    float(*out)[144] = buf1;
    for (int layer = 0; layer < 6; layer++) {
        int set = (layer == 0) ? 0 : (layer < 3 ? 1 : 2);
        int lo = layer + 1;  // valid p range [lo, 140-lo)
        for (int idx = tid; idx < 1400; idx += 256) {
            int o = idx / 140, p = idx - o * 140;
            if (p >= lo && p < 140 - lo) {
                float s = Bs[set][o];
#pragma unroll
                for (int c = 0; c < 10; c++) {
                    const float* ip = &in[c][p];
                    s = fmaf(ip[-1], W[set][o][c][0], s);
                    s = fmaf(ip[0], W[set][o][c][1], s);
                    s = fmaf(ip[1], W[set][o][c][2], s);
                }
                s = s > 0.f ? s : 0.f;
                int g = c0 - 6 + p;
                if (g < 0 || g >= NN) s = 0.f;  // reproduce zero padding at global edges
                out[o][p] = s;
            }
        }
        __syncthreads();
        float(*tmp)[144] = in; in = out; out = tmp;
    }
    // 1x1 conv to 2ch + sigmoid; write the 128 owned cols
    {
        int idx = tid;  // 256 = 2 ch x 128 cols
        int o = idx >> 7, pp = idx & 127;
        int p = 6 + pp;
        float s = Bm[o];
#pragma unroll
        for (int c = 0; c < 10; c++) s = fmaf(in[c][p], Wm[o][c], s);
        float sig = 1.f / (1.f + __expf(-s));
        (o ? RIGHT : LEFT)[b * NN + c0 + pp] = sig;
    }
}

// ---------------- k_diagmass: stage exp(diag) tile, compute p, write P + psum atomics --------
// grid 256 = 8 b x 32 i-tiles(64); block 256 = 4 waves; wave wv handles dm1 = wv*16..wv*16+15.
__global__ __launch_bounds__(256) void k_diagmass(const float* __restrict__ x,
                                                  const float* __restrict__ LEFT,
                                                  const float* __restrict__ RIGHT,
                                                  float* __restrict__ P,
                                                  float* __restrict__ psum) {
    __shared__ float T[65][65];   // T[r][dm1] = exp(x[b, i0+r, i0+r+dm1+1]), +1 halo row
    __shared__ float psl[64];
    int b = blockIdx.x >> 5;
    int i0 = (blockIdx.x & 31) << 6;
    int tid = threadIdx.x;

    // stage: 65 rows x 64 diag offsets, coalesced along the row
    for (int idx = tid; idx < 65 * 64; idx += 256) {
        int r = idx >> 6, dm1 = idx & 63;
        int row = i0 + r;
        int col = row + dm1 + 1;
        float v = 0.f;
        if (row < NN && col < NN) v = __expf(x[((size_t)b * NN + row) * NN + col]);
        T[r][dm1] = v;
    }
    __syncthreads();

    int wv = tid >> 6, lane = tid & 63;
    int i = i0 + lane;
    const float* lf = LEFT + b * NN;
    const float* rt = RIGHT + b * NN;
#pragma unroll
    for (int s = 0; s < 16; s++) {
        int dm1 = wv * 16 + s;
        int d = dm1 + 1;
        int L = (NN - 1) - d;
        float p = 0.f;
        if (i < L) {
            float mi = T[lane + 1][dm1] * rt[i + 1] + T[lane][dm1] * lf[d + i];
            float mo = rt[i] + lf[d + 1 + i];
            p = __logf(mi / mo);
            P[((size_t)dm1 * BB + b) * NN + i] = p;
        }
        float s64 = p;
        for (int off = 32; off; off >>= 1) s64 += __shfl_down(s64, off);
        if (lane == 0) psl[dm1] = s64;
    }
    __syncthreads();
    if (tid < 64) atomicAdd(&psum[tid], psl[tid]);
}

// ---------------- k_out: out = P - psum[d]/(8L), f32 ------------------------------------------
__global__ __launch_bounds__(1024) void k_out(const float* __restrict__ P,
                                              const float* __restrict__ psum,
                                              float* __restrict__ outp) {
    int dm1 = blockIdx.x >> 2, q = blockIdx.x & 3;
    int d = dm1 + 1;
    int L = (NN - 1) - d;
    int tid = threadIdx.x;
    int b2 = tid >> 9, ii = tid & 511;
    int i = q * 512 + ii;
    if (i >= L) return;
    float mean = psum[dm1] / (float)(8 * L);
    size_t off0 = (size_t)dm1 * (NN - 1) - (size_t)dm1 * (dm1 + 1) / 2;
#pragma unroll
    for (int bs = 0; bs < 4; bs++) {
        int b = b2 + bs * 2;
        outp[(size_t)b * TROW + off0 + i] = P[((size_t)dm1 * BB + b) * NN + i] - mean;
    }
}

extern "C" void kernel_launch(void* const* d_in, const int* in_sizes, int n_in,
                              void* d_out, int out_size, void* d_ws, size_t ws_size,
                              hipStream_t stream) {
    const float* x = (const float*)d_in[0];
    const float* wl = (const float*)d_in[1];
    const float* bl = (const float*)d_in[2];
    const float* wr = (const float*)d_in[3];
    const float* br = (const float*)d_in[4];
    const float* wA = (const float*)d_in[5];
    const float* bA = (const float*)d_in[6];
    const float* wB = (const float*)d_in[7];
    const float* bB = (const float*)d_in[8];
    const float* wT = (const float*)d_in[9];
    const float* bT = (const float*)d_in[10];
    const float* wm = (const float*)d_in[11];
    const float* bm = (const float*)d_in[12];

    float* ws = (float*)d_ws;
    float* R    = ws;              // 8*2048*16        = 262144 f
    float* CSp  = ws + 262144;     // 16*8*16*2048     = 4194304 f
    float* WF   = ws + 4456448;    // 2048*16          = 32768 f
    float* CS   = ws + 4489216;    // 8*16*2048        = 262144 f
    float* LEFT = ws + 4751360;    // 8*2048           = 16384 f
    float* RIGHT= ws + 4767744;    // 8*2048           = 16384 f
    float* P    = ws + 4784128;    // 64*8*2048        = 1048576 f
    float* psum = ws + 5832704;    // 64 f

    k_left<<<2048, 256, 0, stream>>>(x, wl, wr, R, WF, psum);
    k_right<<<256, 512, 0, stream>>>(x, WF, CSp);
    k_csum<<<256, 256, 0, stream>>>(CSp, CS);
    k_chainC<<<128, 256, 0, stream>>>(R, CS, bl, br, wA, bA, wB, bB, wT, bT, wm, bm, LEFT, RIGHT);
    k_diagmass<<<256, 256, 0, stream>>>(x, LEFT, RIGHT, P, psum);
    k_out<<<256, 1024, 0, stream>>>(P, psum, (float*)d_out);
}

// Round 7
// 329.509 us; speedup vs baseline: 1.1277x; 1.0004x over previous
//
#include <hip/hip_runtime.h>
#include <hip/hip_bf16.h>

#define NN 2048
#define BB 8
#define TROW 128928   // sum_{d=1..64} (2047-d)

// ---------------- k_left: R[b][i][k] = dot(x[b,i,:], wl[k,:]), k=(c*3+dh) in [0,15) ----------
// grid 2048 = 8 b x 256 rowgroups(8 rows); block 256 = 4 waves; wave handles 2 rows (30 acc).
// K-loop batched: 8 x-loads (4 segs x 2 rows) issued before each FMA block -> deep MLP.
// Side jobs: blocks 0..127 fill WF (transposed wr); block 0 zeroes psum.
__global__ __launch_bounds__(256) void k_left(const float* __restrict__ x,
                                              const float* __restrict__ wl,
                                              const float* __restrict__ wr,
                                              float* __restrict__ R,
                                              float* __restrict__ WF,
                                              float* __restrict__ psum) {
    if (blockIdx.x == 0 && threadIdx.x < 64) psum[threadIdx.x] = 0.f;
    if (blockIdx.x < 128) {
        int idx = blockIdx.x * 256 + threadIdx.x;  // 32768 = 2048*16
        int h = idx >> 4, k = idx & 15;
        float v = 0.f;
        if (k < 15) {
            int c = k / 3, dw = k - c * 3;
            v = wr[c * (NN * 3) + h * 3 + dw];
        }
        WF[idx] = v;
    }
    __shared__ float red[4][30 * 65];
    int b = blockIdx.x >> 8;
    int rg = blockIdx.x & 255;
    int wv = threadIdx.x >> 6, lane = threadIdx.x & 63;
    int r0 = rg * 8 + wv * 2;
    const float* xp = x + ((size_t)(b * NN + r0)) * NN;

    float acc[2][15];
#pragma unroll
    for (int r = 0; r < 2; r++)
#pragma unroll
        for (int k = 0; k < 15; k++) acc[r][k] = 0.f;

#pragma unroll
    for (int half = 0; half < 2; half++) {
        int jb = half * 1024 + lane * 4;
        float4 xv[2][4];
#pragma unroll
        for (int s = 0; s < 4; s++)
#pragma unroll
            for (int r = 0; r < 2; r++)
                xv[r][s] = *(const float4*)(xp + (size_t)r * NN + jb + s * 256);
#pragma unroll
        for (int s = 0; s < 4; s++) {
            int j0 = jb + s * 256;
#pragma unroll
            for (int k = 0; k < 15; k++) {
                float4 w4 = *(const float4*)(wl + (size_t)k * NN + j0);
#pragma unroll
                for (int r = 0; r < 2; r++) {
                    acc[r][k] = fmaf(xv[r][s].x, w4.x, acc[r][k]);
                    acc[r][k] = fmaf(xv[r][s].y, w4.y, acc[r][k]);
                    acc[r][k] = fmaf(xv[r][s].z, w4.z, acc[r][k]);
                    acc[r][k] = fmaf(xv[r][s].w, w4.w, acc[r][k]);
                }
            }
        }
    }
#pragma unroll
    for (int r = 0; r < 2; r++)
#pragma unroll
        for (int k = 0; k < 15; k++) red[wv][(r * 15 + k) * 65 + lane] = acc[r][k];
    __syncthreads();
    if (lane < 30) {
        const float* rp = &red[wv][lane * 65];
        float s = 0.f;
#pragma unroll
        for (int j = 0; j < 64; j++) s += rp[j];
        int r = lane / 15, k = lane - r * 15;
        R[(size_t)(b * NN + r0 + r) * 16 + k] = s;
    }
}

// ---------------- k_right: CSp[rc][b][k][j] = sum_{h in rc chunk} x[b,h,j]*WF[h][k] ----------
// grid 256 = 8 b x 2 jc(1024 cols) x 16 rc(128 rows); block 512 = 8 waves.
// Wave owns 128 cols (lane*2 within), iterates ALL 128 rows -> complete partial, no LDS.
// Weights via block-uniform loads from WF (s_load path). 30 acc/thread, 8 loads in flight.
__global__ __launch_bounds__(512) void k_right(const float* __restrict__ x,
                                               const float* __restrict__ WF,
                                               float* __restrict__ CSp) {
    int b = blockIdx.x >> 5;
    int rem = blockIdx.x & 31;
    int jc = rem >> 4, rc = rem & 15;
    int r0 = rc * 128;
    int w = threadIdx.x >> 6, lane = threadIdx.x & 63;
    int c0 = jc * 1024 + w * 128 + lane * 2;
    const float* xp = x + ((size_t)b * NN + r0) * NN + c0;

    float acc[15][2];
#pragma unroll
    for (int k = 0; k < 15; k++) { acc[k][0] = 0.f; acc[k][1] = 0.f; }

    for (int rb = 0; rb < 16; rb++) {
        float2 xv[8];
#pragma unroll
        for (int q = 0; q < 8; q++)
            xv[q] = *(const float2*)(xp + (size_t)(rb * 8 + q) * NN);
#pragma unroll
        for (int q = 0; q < 8; q++) {
            const float* wrow = WF + (size_t)(r0 + rb * 8 + q) * 16;  // block-uniform -> SGPR
#pragma unroll
            for (int k = 0; k < 15; k++) {
                float wk = wrow[k];
                acc[k][0] = fmaf(xv[q].x, wk, acc[k][0]);
                acc[k][1] = fmaf(xv[q].y, wk, acc[k][1]);
            }
        }
    }
    float* outp = CSp + ((size_t)(rc * BB + b) * 16) * NN + c0;
#pragma unroll
    for (int k = 0; k < 15; k++) {
        float2 v; v.x = acc[k][0]; v.y = acc[k][1];
        *(float2*)(outp + (size_t)k * NN) = v;
    }
}

// ---------------- k_csum: CS[b][k][j] = sum_{rc<16} CSp[rc][b][k][j] -------------------------
// grid 256 x block 256; thread handles one float4 (65536 total).
__global__ __launch_bounds__(256) void k_csum(const float* __restrict__ CSp,
                                              float* __restrict__ CS) {
    int vid = blockIdx.x * 256 + threadIdx.x;  // float4 index in [0, 65536)
    const float4* src = (const float4*)CSp;
    float4 s = src[vid];
#pragma unroll
    for (int rc = 1; rc < 16; rc++) {
        float4 v = src[vid + rc * 65536];
        s.x += v.x; s.y += v.y; s.z += v.z; s.w += v.w;
    }
    ((float4*)CS)[vid] = s;
}

// ---------------- k_chainC: combine(R,CS)+bias -> 6 conv layers -> sigmoid head --------------
// grid 128 = 8 b x 16 chunks(128 cols); halo 6 each side -> ext 140 positions.
__global__ __launch_bounds__(256) void k_chainC(const float* __restrict__ R,
                                                const float* __restrict__ CS,
                                                const float* __restrict__ bl,
                                                const float* __restrict__ br,
                                                const float* __restrict__ wA, const float* __restrict__ bA,
                                                const float* __restrict__ wB, const float* __restrict__ bB,
                                                const float* __restrict__ wT, const float* __restrict__ bT,
                                                const float* __restrict__ wm, const float* __restrict__ bm,
                                                float* __restrict__ LEFT, float* __restrict__ RIGHT) {
    __shared__ float buf0[10][144], buf1[10][144];
    __shared__ float W[3][10][10][3];
    __shared__ float Bs[3][10];
    __shared__ float Wm[2][10], Bm[2];
    int b = blockIdx.x >> 4;
    int c0 = (blockIdx.x & 15) << 7;
    int tid = threadIdx.x;

    for (int idx = tid; idx < 900; idx += 256) {
        int set = idx / 300, rem = idx - set * 300;
        int o = rem / 30, rem2 = rem - o * 30, c = rem2 / 3, kk = rem2 - c * 3;
        float u;
        if (set == 0) u = wA[o * 30 + c * 3 + kk];
        else if (set == 1) u = wB[o * 30 + c * 3 + kk];
        else u = wT[c * 30 + o * 3 + (2 - kk)];   // wTc[o,c,k] = wT[c,o,2-k]
        W[set][o][c][kk] = u;
    }
    if (tid < 30) {
        float v = (tid < 10) ? bA[tid] : (tid < 20) ? bB[tid - 10] : bT[tid - 20];
        Bs[tid / 10][tid % 10] = v;
    }
    if (tid < 20) Wm[tid / 10][tid % 10] = wm[tid];
    if (tid < 2) Bm[tid] = bm[tid];

    // fused combine: build the 10x140 input window directly from R / CS
    for (int idx = tid; idx < 1400; idx += 256) {
        int ch = idx / 140, p = idx - ch * 140;
        int g = c0 - 6 + p;
        float v = 0.f;
        if (g >= 0 && g < NN) {
            if (ch < 5) {
                v = bl[ch];
#pragma unroll
                for (int dh = 0; dh < 3; dh++) {
                    int r = g + dh - 1;
                    if (r >= 0 && r < NN) v += R[(size_t)(b * NN + r) * 16 + ch * 3 + dh];
                }
            } else {
                int c = ch - 5;
                v = br[c];
#pragma unroll
                for (int dw = 0; dw < 3; dw++) {
                    int j = g + dw - 1;
                    if (j >= 0 && j < NN)
                        v += CS[((size_t)b * 16 + c * 3 + dw) * NN + j];
                }
            }
        }
        buf0[ch][p] = v;
    }
    __syncthreads();

    float(*in)[144] = buf0;
    float(*out)[144] = buf1;
    for (int layer = 0; layer < 6; layer++) {
        int set = (layer == 0) ? 0 : (layer < 3 ? 1 : 2);
        int lo = layer + 1;  // valid p range [lo, 140-lo)
        for (int idx = tid; idx < 1400; idx += 256) {
            int o = idx / 140, p = idx - o * 140;
            if (p >= lo && p < 140 - lo) {
                float s = Bs[set][o];
#pragma unroll
                for (int c = 0; c < 10; c++) {
                    const float* ip = &in[c][p];
                    s = fmaf(ip[-1], W[set][o][c][0], s);
                    s = fmaf(ip[0], W[set][o][c][1], s);
                    s = fmaf(ip[1], W[set][o][c][2], s);
                }
                s = s > 0.f ? s : 0.f;
                int g = c0 - 6 + p;
                if (g < 0 || g >= NN) s = 0.f;  // reproduce zero padding at global edges
                out[o][p] = s;
            }
        }
        __syncthreads();
        float(*tmp)[144] = in; in = out; out = tmp;
    }
    // 1x1 conv to 2ch + sigmoid; write the 128 owned cols
    {
        int idx = tid;  // 256 = 2 ch x 128 cols
        int o = idx >> 7, pp = idx & 127;
        int p = 6 + pp;
        float s = Bm[o];
#pragma unroll
        for (int c = 0; c < 10; c++) s = fmaf(in[c][p], Wm[o][c], s);
        float sig = 1.f / (1.f + __expf(-s));
        (o ? RIGHT : LEFT)[b * NN + c0 + pp] = sig;
    }
}

// ---------------- k_diagmass: stage exp(diag) tile, compute p, write P + psum atomics --------
// grid 256 = 8 b x 32 i-tiles(64); block 256 = 4 waves; wave wv handles dm1 = wv*16..wv*16+15.
__global__ __launch_bounds__(256) void k_diagmass(const float* __restrict__ x,
                                                  const float* __restrict__ LEFT,
                                                  const float* __restrict__ RIGHT,
                                                  float* __restrict__ P,
                                                  float* __restrict__ psum) {
    __shared__ float T[65][65];   // T[r][dm1] = exp(x[b, i0+r, i0+r+dm1+1]), +1 halo row
    __shared__ float psl[64];
    int b = blockIdx.x >> 5;
    int i0 = (blockIdx.x & 31) << 6;
    int tid = threadIdx.x;

    // stage: 65 rows x 64 diag offsets, coalesced along the row
    for (int idx = tid; idx < 65 * 64; idx += 256) {
        int r = idx >> 6, dm1 = idx & 63;
        int row = i0 + r;
        int col = row + dm1 + 1;
        float v = 0.f;
        if (row < NN && col < NN) v = __expf(x[((size_t)b * NN + row) * NN + col]);
        T[r][dm1] = v;
    }
    __syncthreads();

    int wv = tid >> 6, lane = tid & 63;
    int i = i0 + lane;
    const float* lf = LEFT + b * NN;
    const float* rt = RIGHT + b * NN;
#pragma unroll
    for (int s = 0; s < 16; s++) {
        int dm1 = wv * 16 + s;
        int d = dm1 + 1;
        int L = (NN - 1) - d;
        float p = 0.f;
        if (i < L) {
            float mi = T[lane + 1][dm1] * rt[i + 1] + T[lane][dm1] * lf[d + i];
            float mo = rt[i] + lf[d + 1 + i];
            p = __logf(mi / mo);
            P[((size_t)dm1 * BB + b) * NN + i] = p;
        }
        float s64 = p;
        for (int off = 32; off; off >>= 1) s64 += __shfl_down(s64, off);
        if (lane == 0) psl[dm1] = s64;
    }
    __syncthreads();
    if (tid < 64) atomicAdd(&psum[tid], psl[tid]);
}

// ---------------- k_out: out = P - psum[d]/(8L), f32 ------------------------------------------
__global__ __launch_bounds__(1024) void k_out(const float* __restrict__ P,
                                              const float* __restrict__ psum,
                                              float* __restrict__ outp) {
    int dm1 = blockIdx.x >> 2, q = blockIdx.x & 3;
    int d = dm1 + 1;
    int L = (NN - 1) - d;
    int tid = threadIdx.x;
    int b2 = tid >> 9, ii = tid & 511;
    int i = q * 512 + ii;
    if (i >= L) return;
    float mean = psum[dm1] / (float)(8 * L);
    size_t off0 = (size_t)dm1 * (NN - 1) - (size_t)dm1 * (dm1 + 1) / 2;
#pragma unroll
    for (int bs = 0; bs < 4; bs++) {
        int b = b2 + bs * 2;
        outp[(size_t)b * TROW + off0 + i] = P[((size_t)dm1 * BB + b) * NN + i] - mean;
    }
}

extern "C" void kernel_launch(void* const* d_in, const int* in_sizes, int n_in,
                              void* d_out, int out_size, void* d_ws, size_t ws_size,
                              hipStream_t stream) {
    const float* x = (const float*)d_in[0];
    const float* wl = (const float*)d_in[1];
    const float* bl = (const float*)d_in[2];
    const float* wr = (const float*)d_in[3];
    const float* br = (const float*)d_in[4];
    const float* wA = (const float*)d_in[5];
    const float* bA = (const float*)d_in[6];
    const float* wB = (const float*)d_in[7];
    const float* bB = (const float*)d_in[8];
    const float* wT = (const float*)d_in[9];
    const float* bT = (const float*)d_in[10];
    const float* wm = (const float*)d_in[11];
    const float* bm = (const float*)d_in[12];

    float* ws = (float*)d_ws;
    float* R    = ws;              // 8*2048*16        = 262144 f
    float* CSp  = ws + 262144;     // 16*8*16*2048     = 4194304 f
    float* WF   = ws + 4456448;    // 2048*16          = 32768 f
    float* CS   = ws + 4489216;    // 8*16*2048        = 262144 f
    float* LEFT = ws + 4751360;    // 8*2048           = 16384 f
    float* RIGHT= ws + 4767744;    // 8*2048           = 16384 f
    float* P    = ws + 4784128;    // 64*8*2048        = 1048576 f
    float* psum = ws + 5832704;    // 64 f

    k_left<<<2048, 256, 0, stream>>>(x, wl, wr, R, WF, psum);
    k_right<<<256, 512, 0, stream>>>(x, WF, CSp);
    k_csum<<<256, 256, 0, stream>>>(CSp, CS);
    k_chainC<<<128, 256, 0, stream>>>(R, CS, bl, br, wA, bA, wB, bB, wT, bT, wm, bm, LEFT, RIGHT);
    k_diagmass<<<256, 256, 0, stream>>>(x, LEFT, RIGHT, P, psum);
    k_out<<<256, 1024, 0, stream>>>(P, psum, (float*)d_out);
}

// Round 8
// 325.926 us; speedup vs baseline: 1.1401x; 1.0110x over previous
//
#include <hip/hip_runtime.h>
#include <hip/hip_bf16.h>

#define NN 2048
#define BB 8
#define TROW 128928   // sum_{d=1..64} (2047-d)

// ---------------- k_left: R[b][i][k] = dot(x[b,i,:], wl[k,:]), k=(c*3+dh) in [0,15) ----------
// grid 2048 = 8 b x 256 rowgroups(8 rows); block 256 = 4 waves; wave handles 2 rows (30 acc).
// Register-lean: 2-seg batches (4 x-loads in flight, 16 VGPR); epilogue folds 64->16 lanes via
// shfl so the LDS buffer is 8.2 KB (not occupancy-binding). Target: 8 waves/SIMD resident.
// Side jobs: blocks 0..127 fill WF (transposed wr); block 0 zeroes psum.
__global__ __launch_bounds__(256) void k_left(const float* __restrict__ x,
                                              const float* __restrict__ wl,
                                              const float* __restrict__ wr,
                                              float* __restrict__ R,
                                              float* __restrict__ WF,
                                              float* __restrict__ psum) {
    if (blockIdx.x == 0 && threadIdx.x < 64) psum[threadIdx.x] = 0.f;
    if (blockIdx.x < 128) {
        int idx = blockIdx.x * 256 + threadIdx.x;  // 32768 = 2048*16
        int h = idx >> 4, k = idx & 15;
        float v = 0.f;
        if (k < 15) {
            int c = k / 3, dw = k - c * 3;
            v = wr[c * (NN * 3) + h * 3 + dw];
        }
        WF[idx] = v;
    }
    __shared__ float red[4][30 * 17];
    int b = blockIdx.x >> 8;
    int rg = blockIdx.x & 255;
    int wv = threadIdx.x >> 6, lane = threadIdx.x & 63;
    int r0 = rg * 8 + wv * 2;
    const float* xp = x + ((size_t)(b * NN + r0)) * NN;

    float acc[2][15];
#pragma unroll
    for (int r = 0; r < 2; r++)
#pragma unroll
        for (int k = 0; k < 15; k++) acc[r][k] = 0.f;

    for (int half = 0; half < 4; half++) {
        int jb = half * 512 + lane * 4;
        float4 xv[2][2];
#pragma unroll
        for (int s = 0; s < 2; s++)
#pragma unroll
            for (int r = 0; r < 2; r++)
                xv[r][s] = *(const float4*)(xp + (size_t)r * NN + jb + s * 256);
#pragma unroll
        for (int s = 0; s < 2; s++) {
            int j0 = jb + s * 256;
#pragma unroll
            for (int k = 0; k < 15; k++) {
                float4 w4 = *(const float4*)(wl + (size_t)k * NN + j0);
#pragma unroll
                for (int r = 0; r < 2; r++) {
                    acc[r][k] = fmaf(xv[r][s].x, w4.x, acc[r][k]);
                    acc[r][k] = fmaf(xv[r][s].y, w4.y, acc[r][k]);
                    acc[r][k] = fmaf(xv[r][s].z, w4.z, acc[r][k]);
                    acc[r][k] = fmaf(xv[r][s].w, w4.w, acc[r][k]);
                }
            }
        }
    }
    // fold 64 lanes -> 16, then small-LDS reduce
#pragma unroll
    for (int r = 0; r < 2; r++)
#pragma unroll
        for (int k = 0; k < 15; k++) {
            float v = acc[r][k];
            v += __shfl_down(v, 32);
            v += __shfl_down(v, 16);
            if (lane < 16) red[wv][(r * 15 + k) * 17 + lane] = v;
        }
    __syncthreads();
    if (lane < 30) {
        const float* rp = &red[wv][lane * 17];
        float s = 0.f;
#pragma unroll
        for (int j = 0; j < 16; j++) s += rp[j];
        int r = lane / 15, k = lane - r * 15;
        R[(size_t)(b * NN + r0 + r) * 16 + k] = s;
    }
}

// ---------------- k_right: CSp[rc][b][k][j] = sum_{h in rc chunk} x[b,h,j]*WF[h][k] ----------
// grid 256 = 8 b x 2 jc(1024 cols) x 16 rc(128 rows); block 512 = 8 waves.
// Wave owns 128 cols (lane*2 within), iterates ALL 128 rows -> complete partial, no LDS.
// Weights via block-uniform loads from WF (s_load path). 30 acc/thread, 8 loads in flight.
__global__ __launch_bounds__(512) void k_right(const float* __restrict__ x,
                                               const float* __restrict__ WF,
                                               float* __restrict__ CSp) {
    int b = blockIdx.x >> 5;
    int rem = blockIdx.x & 31;
    int jc = rem >> 4, rc = rem & 15;
    int r0 = rc * 128;
    int w = threadIdx.x >> 6, lane = threadIdx.x & 63;
    int c0 = jc * 1024 + w * 128 + lane * 2;
    const float* xp = x + ((size_t)b * NN + r0) * NN + c0;

    float acc[15][2];
#pragma unroll
    for (int k = 0; k < 15; k++) { acc[k][0] = 0.f; acc[k][1] = 0.f; }

    for (int rb = 0; rb < 16; rb++) {
        float2 xv[8];
#pragma unroll
        for (int q = 0; q < 8; q++)
            xv[q] = *(const float2*)(xp + (size_t)(rb * 8 + q) * NN);
#pragma unroll
        for (int q = 0; q < 8; q++) {
            const float* wrow = WF + (size_t)(r0 + rb * 8 + q) * 16;  // block-uniform -> SGPR
#pragma unroll
            for (int k = 0; k < 15; k++) {
                float wk = wrow[k];
                acc[k][0] = fmaf(xv[q].x, wk, acc[k][0]);
                acc[k][1] = fmaf(xv[q].y, wk, acc[k][1]);
            }
        }
    }
    float* outp = CSp + ((size_t)(rc * BB + b) * 16) * NN + c0;
#pragma unroll
    for (int k = 0; k < 15; k++) {
        float2 v; v.x = acc[k][0]; v.y = acc[k][1];
        *(float2*)(outp + (size_t)k * NN) = v;
    }
}

// ---------------- k_csum: CS[b][k][j] = sum_{rc<16} CSp[rc][b][k][j] -------------------------
// grid 256 x block 256; thread handles one float4 (65536 total).
__global__ __launch_bounds__(256) void k_csum(const float* __restrict__ CSp,
                                              float* __restrict__ CS) {
    int vid = blockIdx.x * 256 + threadIdx.x;  // float4 index in [0, 65536)
    const float4* src = (const float4*)CSp;
    float4 s = src[vid];
#pragma unroll
    for (int rc = 1; rc < 16; rc++) {
        float4 v = src[vid + rc * 65536];
        s.x += v.x; s.y += v.y; s.z += v.z; s.w += v.w;
    }
    ((float4*)CS)[vid] = s;
}

// ---------------- k_chainC: combine(R,CS)+bias -> 6 conv layers -> sigmoid head --------------
// grid 128 = 8 b x 16 chunks(128 cols); halo 6 each side -> ext 140 positions.
__global__ __launch_bounds__(256) void k_chainC(const float* __restrict__ R,
                                                const float* __restrict__ CS,
                                                const float* __restrict__ bl,
                                                const float* __restrict__ br,
                                                const float* __restrict__ wA, const float* __restrict__ bA,
                                                const float* __restrict__ wB, const float* __restrict__ bB,
                                                const float* __restrict__ wT, const float* __restrict__ bT,
                                                const float* __restrict__ wm, const float* __restrict__ bm,
                                                float* __restrict__ LEFT, float* __restrict__ RIGHT) {
    __shared__ float buf0[10][144], buf1[10][144];
    __shared__ float W[3][10][10][3];
    __shared__ float Bs[3][10];
    __shared__ float Wm[2][10], Bm[2];
    int b = blockIdx.x >> 4;
    int c0 = (blockIdx.x & 15) << 7;
    int tid = threadIdx.x;

    for (int idx = tid; idx < 900; idx += 256) {
        int set = idx / 300, rem = idx - set * 300;
        int o = rem / 30, rem2 = rem - o * 30, c = rem2 / 3, kk = rem2 - c * 3;
        float u;
        if (set == 0) u = wA[o * 30 + c * 3 + kk];
        else if (set == 1) u = wB[o * 30 + c * 3 + kk];
        else u = wT[c * 30 + o * 3 + (2 - kk)];   // wTc[o,c,k] = wT[c,o,2-k]
        W[set][o][c][kk] = u;
    }
    if (tid < 30) {
        float v = (tid < 10) ? bA[tid] : (tid < 20) ? bB[tid - 10] : bT[tid - 20];
        Bs[tid / 10][tid % 10] = v;
    }
    if (tid < 20) Wm[tid / 10][tid % 10] = wm[tid];
    if (tid < 2) Bm[tid] = bm[tid];

    // fused combine: build the 10x140 input window directly from R / CS
    for (int idx = tid; idx < 1400; idx += 256) {
        int ch = idx / 140, p = idx - ch * 140;
        int g = c0 - 6 + p;
        float v = 0.f;
        if (g >= 0 && g < NN) {
            if (ch < 5) {
                v = bl[ch];
#pragma unroll
                for (int dh = 0; dh < 3; dh++) {
                    int r = g + dh - 1;
                    if (r >= 0 && r < NN) v += R[(size_t)(b * NN + r) * 16 + ch * 3 + dh];
                }
            } else {
                int c = ch - 5;
                v = br[c];
#pragma unroll
                for (int dw = 0; dw < 3; dw++) {
                    int j = g + dw - 1;
                    if (j >= 0 && j < NN)
                        v += CS[((size_t)b * 16 + c * 3 + dw) * NN + j];
                }
            }
        }
        buf0[ch][p] = v;
    }
    __syncthreads();

    float(*in)[144] = buf0;
    float(*out)[144] = buf1;
    for (int layer = 0; layer < 6; layer++) {
        int set = (layer == 0) ? 0 : (layer < 3 ? 1 : 2);
        int lo = layer + 1;  // valid p range [lo, 140-lo)
        for (int idx = tid; idx < 1400; idx += 256) {
            int o = idx / 140, p = idx - o * 140;
            if (p >= lo && p < 140 - lo) {
                float s = Bs[set][o];
#pragma unroll
                for (int c = 0; c < 10; c++) {
                    const float* ip = &in[c][p];
                    s = fmaf(ip[-1], W[set][o][c][0], s);
                    s = fmaf(ip[0], W[set][o][c][1], s);
                    s = fmaf(ip[1], W[set][o][c][2], s);
                }
                s = s > 0.f ? s : 0.f;
                int g = c0 - 6 + p;
                if (g < 0 || g >= NN) s = 0.f;  // reproduce zero padding at global edges
                out[o][p] = s;
            }
        }
        __syncthreads();
        float(*tmp)[144] = in; in = out; out = tmp;
    }
    // 1x1 conv to 2ch + sigmoid; write the 128 owned cols
    {
        int idx = tid;  // 256 = 2 ch x 128 cols
        int o = idx >> 7, pp = idx & 127;
        int p = 6 + pp;
        float s = Bm[o];
#pragma unroll
        for (int c = 0; c < 10; c++) s = fmaf(in[c][p], Wm[o][c], s);
        float sig = 1.f / (1.f + __expf(-s));
        (o ? RIGHT : LEFT)[b * NN + c0 + pp] = sig;
    }
}

// ---------------- k_diagmass: stage exp(diag) tile, compute p, write P + psum atomics --------
// grid 256 = 8 b x 32 i-tiles(64); block 256 = 4 waves; wave wv handles dm1 = wv*16..wv*16+15.
__global__ __launch_bounds__(256) void k_diagmass(const float* __restrict__ x,
                                                  const float* __restrict__ LEFT,
                                                  const float* __restrict__ RIGHT,
                                                  float* __restrict__ P,
                                                  float* __restrict__ psum) {
    __shared__ float T[65][65];   // T[r][dm1] = exp(x[b, i0+r, i0+r+dm1+1]), +1 halo row
    __shared__ float psl[64];
    int b = blockIdx.x >> 5;
    int i0 = (blockIdx.x & 31) << 6;
    int tid = threadIdx.x;

    // stage: 65 rows x 64 diag offsets, coalesced along the row
    for (int idx = tid; idx < 65 * 64; idx += 256) {
        int r = idx >> 6, dm1 = idx & 63;
        int row = i0 + r;
        int col = row + dm1 + 1;
        float v = 0.f;
        if (row < NN && col < NN) v = __expf(x[((size_t)b * NN + row) * NN + col]);
        T[r][dm1] = v;
    }
    __syncthreads();

    int wv = tid >> 6, lane = tid & 63;
    int i = i0 + lane;
    const float* lf = LEFT + b * NN;
    const float* rt = RIGHT + b * NN;
#pragma unroll
    for (int s = 0; s < 16; s++) {
        int dm1 = wv * 16 + s;
        int d = dm1 + 1;
        int L = (NN - 1) - d;
        float p = 0.f;
        if (i < L) {
            float mi = T[lane + 1][dm1] * rt[i + 1] + T[lane][dm1] * lf[d + i];
            float mo = rt[i] + lf[d + 1 + i];
            p = __logf(mi / mo);
            P[((size_t)dm1 * BB + b) * NN + i] = p;
        }
        float s64 = p;
        for (int off = 32; off; off >>= 1) s64 += __shfl_down(s64, off);
        if (lane == 0) psl[dm1] = s64;
    }
    __syncthreads();
    if (tid < 64) atomicAdd(&psum[tid], psl[tid]);
}

// ---------------- k_out: out = P - psum[d]/(8L), f32 ------------------------------------------
__global__ __launch_bounds__(1024) void k_out(const float* __restrict__ P,
                                              const float* __restrict__ psum,
                                              float* __restrict__ outp) {
    int dm1 = blockIdx.x >> 2, q = blockIdx.x & 3;
    int d = dm1 + 1;
    int L = (NN - 1) - d;
    int tid = threadIdx.x;
    int b2 = tid >> 9, ii = tid & 511;
    int i = q * 512 + ii;
    if (i >= L) return;
    float mean = psum[dm1] / (float)(8 * L);
    size_t off0 = (size_t)dm1 * (NN - 1) - (size_t)dm1 * (dm1 + 1) / 2;
#pragma unroll
    for (int bs = 0; bs < 4; bs++) {
        int b = b2 + bs * 2;
        outp[(size_t)b * TROW + off0 + i] = P[((size_t)dm1 * BB + b) * NN + i] - mean;
    }
}

extern "C" void kernel_launch(void* const* d_in, const int* in_sizes, int n_in,
                              void* d_out, int out_size, void* d_ws, size_t ws_size,
                              hipStream_t stream) {
    const float* x = (const float*)d_in[0];
    const float* wl = (const float*)d_in[1];
    const float* bl = (const float*)d_in[2];
    const float* wr = (const float*)d_in[3];
    const float* br = (const float*)d_in[4];
    const float* wA = (const float*)d_in[5];
    const float* bA = (const float*)d_in[6];
    const float* wB = (const float*)d_in[7];
    const float* bB = (const float*)d_in[8];
    const float* wT = (const float*)d_in[9];
    const float* bT = (const float*)d_in[10];
    const float* wm = (const float*)d_in[11];
    const float* bm = (const float*)d_in[12];

    float* ws = (float*)d_ws;
    float* R    = ws;              // 8*2048*16        = 262144 f
    float* CSp  = ws + 262144;     // 16*8*16*2048     = 4194304 f
    float* WF   = ws + 4456448;    // 2048*16          = 32768 f
    float* CS   = ws + 4489216;    // 8*16*2048        = 262144 f
    float* LEFT = ws + 4751360;    // 8*2048           = 16384 f
    float* RIGHT= ws + 4767744;    // 8*2048           = 16384 f
    float* P    = ws + 4784128;    // 64*8*2048        = 1048576 f
    float* psum = ws + 5832704;    // 64 f

    k_left<<<2048, 256, 0, stream>>>(x, wl, wr, R, WF, psum);
    k_right<<<256, 512, 0, stream>>>(x, WF, CSp);
    k_csum<<<256, 256, 0, stream>>>(CSp, CS);
    k_chainC<<<128, 256, 0, stream>>>(R, CS, bl, br, wA, bA, wB, bB, wT, bT, wm, bm, LEFT, RIGHT);
    k_diagmass<<<256, 256, 0, stream>>>(x, LEFT, RIGHT, P, psum);
    k_out<<<256, 1024, 0, stream>>>(P, psum, (float*)d_out);
}